// Round 10
// baseline (2324.002 us; speedup 1.0000x reference)
//
#include <hip/hip_runtime.h>

// Problem constants
#define Bn 4
#define Nn 8192
#define Dn 64
#define Sn 2048
#define Kn 32
#define R2c 0.04f          // f32(0.2*0.2)
#define OUT_XYZ (Bn*Sn*3)  // 24576 floats of new_xyz, then feats

// Workspace layout (units = 4-byte elements)
#define WS_P4  0            // [B*N] float4 {x,y,z,0}
#define WS_WB1 131072       // bf16 W1' [64][96]  (feat-first permute, zero pad)
#define WS_WB2 134144       // bf16 W2  [128][64]
#define WS_WB3 138240       // bf16 W3  [256][128]
#define WS_GRP 154624       // int grp_idx [B*S][K]

#define HSTR 136            // bf16 LDS row stride (128 max C + 8 pad)

typedef __attribute__((ext_vector_type(8))) short short8;
typedef __attribute__((ext_vector_type(4))) float floatx4;
typedef __attribute__((ext_vector_type(2))) float float2v;
typedef unsigned long long ull;

// float -> bf16 (RNE) without relying on header APIs
__device__ __forceinline__ unsigned short f2bf(float f) {
    unsigned u = __float_as_uint(f);
    return (unsigned short)((u + 0x7FFFu + ((u >> 16) & 1u)) >> 16);
}

// ---------------------------------------------------------------------------
// Prep: xyz -> float4 array; weights -> bf16 [O][Cp] row-major.
// ---------------------------------------------------------------------------
__global__ __launch_bounds__(256) void prep_kernel(const float* __restrict__ xyz,
                                                   const float* __restrict__ W1,
                                                   const float* __restrict__ W2,
                                                   const float* __restrict__ W3,
                                                   float* __restrict__ ws) {
    int id = blockIdx.x * 256 + threadIdx.x;
    if (id < Bn * Nn) {
        float4* p4 = (float4*)(ws + WS_P4);
        p4[id] = make_float4(xyz[id * 3 + 0], xyz[id * 3 + 1], xyz[id * 3 + 2], 0.f);
    }
    int i1 = id - Bn * Nn;
    if (i1 >= 0 && i1 < 64 * 96) {
        int o = i1 / 96, c = i1 % 96;
        float v = (c < 64) ? W1[o * 67 + 3 + c] : (c < 67 ? W1[o * 67 + (c - 64)] : 0.f);
        ((unsigned short*)(ws + WS_WB1))[i1] = f2bf(v);
    }
    int i2 = i1 - 64 * 96;
    if (i2 >= 0 && i2 < 128 * 64)
        ((unsigned short*)(ws + WS_WB2))[i2] = f2bf(W2[i2]);
    int i3 = i2 - 128 * 64;
    if (i3 >= 0 && i3 < 256 * 128)
        ((unsigned short*)(ws + WS_WB3))[i3] = f2bf(W3[i3]);
}

// Fused wave-64 lexicographic max of 64-bit keys (hi=dist bits, lo=payload).
// One DPP ladder; 0-injection from bound_ctrl can never win. Result
// broadcast via 2 readlanes from lane 63 (SGPR-uniform).
__device__ __forceinline__ ull wave_kmax_dpp(ull k) {
    unsigned lo = (unsigned)k, hi = (unsigned)(k >> 32);
#define KRUNG(ctl)                                                                          \
    {                                                                                       \
        unsigned tlo = (unsigned)__builtin_amdgcn_update_dpp(0, (int)lo, ctl, 0xf, 0xf, true); \
        unsigned thi = (unsigned)__builtin_amdgcn_update_dpp(0, (int)hi, ctl, 0xf, 0xf, true); \
        ull t = ((ull)thi << 32) | tlo;                                                     \
        ull c = ((ull)hi << 32) | lo;                                                       \
        if (t > c) { hi = thi; lo = tlo; }                                                  \
    }
    KRUNG(0x111) KRUNG(0x112) KRUNG(0x114) KRUNG(0x118) KRUNG(0x142) KRUNG(0x143)
#undef KRUNG
    hi = (unsigned)__builtin_amdgcn_readlane((int)hi, 63);
    lo = (unsigned)__builtin_amdgcn_readlane((int)lo, 63);
    return ((ull)hi << 32) | lo;
}

// key + coord-payload reduce rung
#define REDP(ka, qa, kb, qb)                         \
    {                                                \
        bool t_ = (kb) > (ka);                       \
        ka = t_ ? (kb) : (ka);                       \
        qa.x = t_ ? (qb).x : (qa).x;                 \
        qa.y = t_ ? (qb).y : (qa).y;                 \
        qa.z = t_ ? (qb).z : (qa).z;                 \
    }

// ---------------------------------------------------------------------------
// Farthest point sampling — R8 structure (best: 1504us) + payload exchange.
//
// R8 unchanged: z-sort into 128KB LDS table sP4 (x,y,z,origIdx); wave w owns
// slots [w*1024,(w+1)*1024) in REGISTERS (R9 proved in-loop LDS point reads
// cost +225cy/step); conservative z-bbox skip (bit-exact); pk-packed dist
// math; fused u64 key ladder; parity-double-buffered exchange, ONE
// barrier/step; LDS sHist (R8's fix).
//
// CHANGE vs R8: the post-barrier dependent winner fetch sP4[slot] (~120 cy
// on every wave's serial chain) is deleted. After the ladder, bestK is
// SGPR-uniform, so the winner's (u, owner-lane, half) are uniform: an
// 8-case uniform branch selects the winner coords from the wave's own
// registers, v_readlane lifts them to SGPRs (cached across skipped steps),
// and lane 0 publishes (key,x,y,z); the post-barrier tree reduces keys
// WITH coord payload. Published bits == the register bits loaded from sP4
// in the prologue == what the fetch would have returned -> trajectory
// bit-identical.
// ---------------------------------------------------------------------------
__global__ __launch_bounds__(512, 2) void fps_kernel(const float* __restrict__ ws,
                                                     float* __restrict__ out_xyz) {
    #pragma clang fp contract(off)
    const int b = blockIdx.x;
    const int tid = threadIdx.x;
    const int lane = tid & 63;
    const int wv = tid >> 6;
    const float4* p4 = (const float4*)(ws + WS_P4) + b * Nn;

    __shared__ __align__(16) float4 sP4[Nn];   // 128 KB sorted point table
    __shared__ float sHist[Sn * 3];            // 24 KB per-step centroid record
    __shared__ ull sKey[2][8];
    __shared__ __align__(16) float4 sCrd[2][8];
    __shared__ int sH[256];                    // histogram
    __shared__ int sC[256];                    // cursors (exclusive starts)

    // ---- load original points (coalesced) ----
    float4 t4[16];
    #pragma unroll
    for (int j = 0; j < 16; j++) t4[j] = p4[j * 512 + tid];

    // ---- histogram over 256 z-bins ----
    for (int i = tid; i < 256; i += 512) sH[i] = 0;
    __syncthreads();
    int slt[16];
    #pragma unroll
    for (int j = 0; j < 16; j++) {
        int bin = (int)(t4[j].z * 256.0f);
        bin = bin < 0 ? 0 : (bin > 255 ? 255 : bin);
        slt[j] = bin;
        atomicAdd(&sH[bin], 1);
    }
    __syncthreads();

    // ---- exclusive scan of 256 bins (wave 0, 4 bins/lane) ----
    if (tid < 64) {
        int b4 = tid * 4;
        int h0 = sH[b4], h1 = sH[b4 + 1], h2 = sH[b4 + 2], h3 = sH[b4 + 3];
        int sum = h0 + h1 + h2 + h3;
        int inc = sum;
        #pragma unroll
        for (int off = 1; off < 64; off <<= 1) {
            int o = __shfl_up(inc, off);
            if (tid >= off) inc += o;
        }
        int exc = inc - sum;
        sC[b4]     = exc;
        sC[b4 + 1] = exc + h0;
        sC[b4 + 2] = exc + h0 + h1;
        sC[b4 + 3] = exc + h0 + h1 + h2;
    }
    __syncthreads();

    // ---- claim unique sorted slots, scatter into the table ----
    #pragma unroll
    for (int j = 0; j < 16; j++)
        slt[j] = atomicAdd(&sC[slt[j]], 1);
    #pragma unroll
    for (int j = 0; j < 16; j++)
        sP4[slt[j]] = make_float4(t4[j].x, t4[j].y, t4[j].z,
                                  __int_as_float(j * 512 + tid));
    __syncthreads();

    // ---- slab read: wave wv owns slots [wv*1024, wv*1024+1024) ----
    float2v pX[8], pY[8], pZ[8], dI[8];
    unsigned loA[8], loB[8];
    const int sbase = wv * 1024 + lane * 2;
    #pragma unroll
    for (int u = 0; u < 8; u++) {
        int sa = sbase + u * 128;
        float4 va = sP4[sa];
        float4 vb = sP4[sa + 1];
        pX[u].x = va.x; pX[u].y = vb.x;
        pY[u].x = va.y; pY[u].y = vb.y;
        pZ[u].x = va.z; pZ[u].y = vb.z;
        unsigned ogA = (unsigned)__float_as_int(va.w);
        unsigned ogB = (unsigned)__float_as_int(vb.w);
        loA[u] = ((8191u - ogA) << 13) | (unsigned)sa;
        loB[u] = ((8191u - ogB) << 13) | (unsigned)(sa + 1);
        dI[u].x = 1e10f; dI[u].y = 1e10f;
    }
    #pragma unroll
    for (int u = 0; u < 8; u++)
        asm volatile("" : "+v"(pX[u]), "+v"(pY[u]), "+v"(pZ[u]));

    // ---- wave z-bbox (exact min/max butterfly, one time) ----
    float zl = fminf(pZ[0].x, pZ[0].y);
    float zh = fmaxf(pZ[0].x, pZ[0].y);
    #pragma unroll
    for (int u = 1; u < 8; u++) {
        zl = fminf(zl, fminf(pZ[u].x, pZ[u].y));
        zh = fmaxf(zh, fmaxf(pZ[u].x, pZ[u].y));
    }
    #pragma unroll
    for (int off = 1; off < 64; off <<= 1) {
        zl = fminf(zl, __shfl_xor(zl, off));
        zh = fmaxf(zh, __shfl_xor(zh, off));
    }

    // ---- main FPS loop ----
    float4 c0 = p4[0];
    float cx = c0.x, cy = c0.y, cz = c0.z;
    float wmaxC = 1e30f;     // cached wave max dist (forces first step active)
    ull bestK = 0;           // cached wave best key
    int bXc = 0, bYc = 0, bZc = 0;   // cached wave-winner coords (uniform)

    for (int s = 0; s < Sn; s++) {
        const int par = s & 1;
        if (tid == 0) {       // LDS record: no vmcnt at the barrier
            sHist[s * 3 + 0] = cx;
            sHist[s * 3 + 1] = cy;
            sHist[s * 3 + 2] = cz;
        }

        // conservative slab distance: skip only if provably no dist changes
        float dzb = fmaxf(fmaxf(zl - cz, cz - zh), 0.0f);
        float dz2s = dzb * dzb * 0.999999f;
        if (dz2s < wmaxC) {   // wave-uniform branch
            float nxs = -cx, nys = -cy, nzs = -cz;
            float2v nX, nY, nZ;
            nX.x = nxs; nX.y = nxs;
            nY.x = nys; nY.y = nys;
            nZ.x = nzs; nZ.y = nzs;

            float lv = -1.0f;
            #pragma unroll
            for (int u = 0; u < 8; u++) {
                float2v dx, dy, dz_, xx, yy, zz, s1, d2;
                asm("v_pk_add_f32 %0, %1, %2" : "=v"(dx) : "v"(pX[u]), "v"(nX));
                asm("v_pk_add_f32 %0, %1, %2" : "=v"(dy) : "v"(pY[u]), "v"(nY));
                asm("v_pk_add_f32 %0, %1, %2" : "=v"(dz_) : "v"(pZ[u]), "v"(nZ));
                asm("v_pk_mul_f32 %0, %1, %1" : "=v"(xx) : "v"(dx));
                asm("v_pk_mul_f32 %0, %1, %1" : "=v"(yy) : "v"(dy));
                asm("v_pk_mul_f32 %0, %1, %1" : "=v"(zz) : "v"(dz_));
                asm("v_pk_add_f32 %0, %1, %2" : "=v"(s1) : "v"(xx), "v"(yy));
                asm("v_pk_add_f32 %0, %1, %2" : "=v"(d2) : "v"(s1), "v"(zz));
                float mx = fminf(dI[u].x, d2.x);
                float my = fminf(dI[u].y, d2.y);
                dI[u].x = mx; dI[u].y = my;
                lv = fmaxf(fmaxf(lv, mx), my);   // v_max3_f32
            }

            // lane-tie recovery: max lo among THIS lane's points at lv
            unsigned c[16];
            #pragma unroll
            for (int u = 0; u < 8; u++) {
                c[2 * u]     = (dI[u].x == lv) ? loA[u] : 0u;
                c[2 * u + 1] = (dI[u].y == lv) ? loB[u] : 0u;
            }
            #pragma unroll
            for (int st = 1; st < 16; st <<= 1)
                #pragma unroll
                for (int i = 0; i < 16; i += 2 * st)
                    c[i] = (c[i + st] > c[i]) ? c[i + st] : c[i];

            // fused lexicographic wave reduce
            ull k = ((ull)__float_as_uint(lv) << 32) | (ull)c[0];
            bestK = wave_kmax_dpp(k);
            wmaxC = __uint_as_float((unsigned)(bestK >> 32));

            // extract wave-winner coords from registers (uniform math):
            // slot = wv*1024 + u*128 + ownerLane*2 + hf
            unsigned slotW = (unsigned)(bestK & 0x1FFFull);   // uniform
            int uu = (int)((slotW >> 7) & 7);
            int hf = (int)(slotW & 1);
            int ow = (int)((slotW & 127) >> 1);
            float wx = 0.f, wy = 0.f, wz = 0.f;
            #pragma unroll
            for (int q = 0; q < 8; q++) {
                if (uu == q) {    // uniform branch
                    wx = hf ? pX[q].y : pX[q].x;
                    wy = hf ? pY[q].y : pY[q].x;
                    wz = hf ? pZ[q].y : pZ[q].x;
                }
            }
            bXc = __builtin_amdgcn_readlane(__float_as_int(wx), ow);
            bYc = __builtin_amdgcn_readlane(__float_as_int(wy), ow);
            bZc = __builtin_amdgcn_readlane(__float_as_int(wz), ow);
        }

        if (lane == 0) {
            sKey[par][wv] = bestK;
            sCrd[par][wv] = make_float4(__int_as_float(bXc),
                                        __int_as_float(bYc),
                                        __int_as_float(bZc), 0.f);
        }
        __syncthreads();

        ull a0 = sKey[par][0], a1 = sKey[par][1];
        ull a2 = sKey[par][2], a3 = sKey[par][3];
        ull a4 = sKey[par][4], a5 = sKey[par][5];
        ull a6 = sKey[par][6], a7 = sKey[par][7];
        float4 q0 = sCrd[par][0], q1 = sCrd[par][1];
        float4 q2 = sCrd[par][2], q3 = sCrd[par][3];
        float4 q4 = sCrd[par][4], q5 = sCrd[par][5];
        float4 q6 = sCrd[par][6], q7 = sCrd[par][7];
        REDP(a0, q0, a1, q1);
        REDP(a2, q2, a3, q3);
        REDP(a4, q4, a5, q5);
        REDP(a6, q6, a7, q7);
        REDP(a0, q0, a2, q2);
        REDP(a4, q4, a6, q6);
        REDP(a0, q0, a4, q4);

        cx = q0.x; cy = q0.y; cz = q0.z;   // no dependent winner fetch
    }

    __syncthreads();
    float4* o4 = (float4*)(out_xyz + b * Sn * 3);
    const float4* h4 = (const float4*)sHist;
    #pragma unroll
    for (int i = tid; i < Sn * 3 / 4; i += 512) o4[i] = h4[i];
}

// ---------------------------------------------------------------------------
// Ball query (unchanged; exact-decision verified: absmax 0.0).
// ---------------------------------------------------------------------------
__global__ __launch_bounds__(256) void ballq_kernel(const float* __restrict__ ws,
                                                    const float* __restrict__ newxyz,
                                                    int* __restrict__ grp) {
    #pragma clang fp contract(off)
    int t = blockIdx.x * 256 + threadIdx.x;
    int wid = t >> 6;
    int lane = t & 63;
    int b = wid >> 11;
    const float4* p4 = (const float4*)(ws + WS_P4) + b * Nn;

    float nx = newxyz[wid * 3 + 0], ny = newxyz[wid * 3 + 1], nz = newxyz[wid * 3 + 2];
    float a2 = (nx * nx + ny * ny) + nz * nz;

    int total = 0;
    int firstp = 0;
    for (int c = 0; c < Nn / 64; c++) {
        int p = c * 64 + lane;
        float4 v = p4[p];
        float x = v.x, y = v.y, z = v.z;
        float bv = (x * x + y * y) + z * z;
        float dot = __builtin_fmaf(nx, x, 0.0f);
        dot = __builtin_fmaf(ny, y, dot);
        dot = __builtin_fmaf(nz, z, dot);
        float sq = (a2 + bv) - 2.0f * dot;
        bool hit = !(sq > R2c);
        unsigned long long mask = __ballot(hit);
        if (mask) {
            if (total == 0) firstp = c * 64 + (__ffsll(mask) - 1);
            int rank = __popcll(mask & ((1ull << lane) - 1ull));
            int slot = total + rank;
            if (hit && slot < Kn) grp[wid * Kn + slot] = p;
            total += (int)__popcll(mask);
            if (total >= Kn) break;
        }
    }
    if (lane >= total && lane < Kn) grp[wid * Kn + lane] = firstp;
}

// ---------------------------------------------------------------------------
// MFMA MLP (unchanged): one group per block, 256 threads = 4 waves.
// ---------------------------------------------------------------------------
template<int KB, int O>
__device__ __forceinline__ void mfma_layer(const unsigned short* __restrict__ X,
                                           unsigned short* __restrict__ Y,
                                           const unsigned short* __restrict__ wb,
                                           const float* __restrict__ bias,
                                           int lane, int wv) {
    const int Cp = KB * 32;
    const int mt = wv & 1;
    const int mrow = mt * 16 + (lane & 15);
    const int quad = lane >> 4;

    short8 a[KB];
    #pragma unroll
    for (int kb = 0; kb < KB; kb++)
        a[kb] = *(const short8*)&X[mrow * HSTR + kb * 32 + quad * 8];

    for (int nt = (wv >> 1); nt < O / 16; nt += 2) {
        int n0 = nt * 16;
        float bv = bias[n0 + (lane & 15)];
        floatx4 acc = {bv, bv, bv, bv};
        #pragma unroll
        for (int kb = 0; kb < KB; kb++) {
            short8 bf = *(const short8*)&wb[(n0 + (lane & 15)) * Cp + kb * 32 + quad * 8];
            acc = __builtin_amdgcn_mfma_f32_16x16x32_bf16(a[kb], bf, acc, 0, 0, 0);
        }
        #pragma unroll
        for (int r = 0; r < 4; r++) {
            float v = fmaxf(acc[r], 0.f);
            int m = mt * 16 + quad * 4 + r;
            Y[m * HSTR + n0 + (lane & 15)] = f2bf(v);
        }
    }
}

__global__ __launch_bounds__(256) void mlp_kernel(const float* __restrict__ xyz,
                                                  const float* __restrict__ feat,
                                                  const float* __restrict__ ws,
                                                  const int* __restrict__ grp,
                                                  const float* __restrict__ b1,
                                                  const float* __restrict__ b2,
                                                  const float* __restrict__ b3,
                                                  float* __restrict__ out) {
    __shared__ __align__(16) unsigned short hA[32 * HSTR];
    __shared__ __align__(16) unsigned short hB[32 * HSTR];
    __shared__ float mxs[2][256];
    __shared__ int   sIdx[Kn];
    __shared__ float sCent[3];

    int g = blockIdx.x;            // b*S + s
    int b = g >> 11;
    int tid = threadIdx.x;
    int lane = tid & 63, wv = tid >> 6;

    if (tid < Kn) sIdx[tid] = grp[g * Kn + tid];
    if (tid == 0) { sCent[0] = out[g*3]; sCent[1] = out[g*3+1]; sCent[2] = out[g*3+2]; }
    // zero hA (pad cols must be 0 for the K=96 layer)
    {
        short8 z = {0,0,0,0,0,0,0,0};
        for (int i = tid; i < 32 * HSTR / 8; i += 256)
            ((short8*)hA)[i] = z;
    }
    __syncthreads();

    { // stage h0: feats -> cols 0..63 (bf16x8 vector writes), xyz -> 64..66
        int m = tid >> 3, m8 = tid & 7;
        int idx = sIdx[m];
        int base = b * Nn + idx;
        const float4* f4 = (const float4*)(feat + base * 64 + m8 * 8);
        float4 va = f4[0], vb = f4[1];
        short8 pk;
        pk[0] = (short)f2bf(va.x); pk[1] = (short)f2bf(va.y);
        pk[2] = (short)f2bf(va.z); pk[3] = (short)f2bf(va.w);
        pk[4] = (short)f2bf(vb.x); pk[5] = (short)f2bf(vb.y);
        pk[6] = (short)f2bf(vb.z); pk[7] = (short)f2bf(vb.w);
        *(short8*)&hA[m * HSTR + m8 * 8] = pk;
        if (m8 == 0) {
            hA[m * HSTR + 64] = f2bf(xyz[base * 3 + 0] - sCent[0]);
            hA[m * HSTR + 65] = f2bf(xyz[base * 3 + 1] - sCent[1]);
            hA[m * HSTR + 66] = f2bf(xyz[base * 3 + 2] - sCent[2]);
        }
    }
    __syncthreads();

    const unsigned short* wb1 = (const unsigned short*)(ws + WS_WB1);
    const unsigned short* wb2 = (const unsigned short*)(ws + WS_WB2);
    const unsigned short* wb3 = (const unsigned short*)(ws + WS_WB3);

    mfma_layer<3, 64>(hA, hB, wb1, b1, lane, wv);     // 96 -> 64
    __syncthreads();
    mfma_layer<2, 128>(hB, hA, wb2, b2, lane, wv);    // 64 -> 128
    __syncthreads();

    { // L3 (128 -> 256) + fused maxpool
        const int mt = wv & 1;
        const int mrow = mt * 16 + (lane & 15);
        const int quad = lane >> 4;
        short8 a[4];
        #pragma unroll
        for (int kb = 0; kb < 4; kb++)
            a[kb] = *(const short8*)&hA[mrow * HSTR + kb * 32 + quad * 8];
        for (int nt = (wv >> 1); nt < 16; nt += 2) {
            int n0 = nt * 16;
            float bv = b3[n0 + (lane & 15)];
            floatx4 acc = {bv, bv, bv, bv};
            #pragma unroll
            for (int kb = 0; kb < 4; kb++) {
                short8 bf = *(const short8*)&wb3[(n0 + (lane & 15)) * 128 + kb * 32 + quad * 8];
                acc = __builtin_amdgcn_mfma_f32_16x16x32_bf16(a[kb], bf, acc, 0, 0, 0);
            }
            float pm = fmaxf(fmaxf(fmaxf(acc[0], acc[1]), fmaxf(acc[2], acc[3])), 0.f);
            pm = fmaxf(pm, __shfl_xor(pm, 16));   // reduce across the 4 quads
            pm = fmaxf(pm, __shfl_xor(pm, 32));
            if (lane < 16) mxs[mt][n0 + lane] = pm;
        }
    }
    __syncthreads();

    out[OUT_XYZ + g * 256 + tid] = fmaxf(mxs[0][tid], mxs[1][tid]);
}

// ---------------------------------------------------------------------------
extern "C" void kernel_launch(void* const* d_in, const int* in_sizes, int n_in,
                              void* d_out, int out_size, void* d_ws, size_t ws_size,
                              hipStream_t stream) {
    const float* xyz  = (const float*)d_in[0];
    const float* feat = (const float*)d_in[1];
    const float* W1   = (const float*)d_in[2];
    const float* b1   = (const float*)d_in[3];
    const float* W2   = (const float*)d_in[4];
    const float* b2   = (const float*)d_in[5];
    const float* W3   = (const float*)d_in[6];
    const float* b3   = (const float*)d_in[7];
    float* out = (float*)d_out;
    float* ws  = (float*)d_ws;
    int*   grp = (int*)d_ws + WS_GRP;

    hipLaunchKernelGGL(prep_kernel, dim3(312), dim3(256), 0, stream, xyz, W1, W2, W3, ws);
    hipLaunchKernelGGL(fps_kernel, dim3(Bn), dim3(512), 0, stream, ws, out);
    hipLaunchKernelGGL(ballq_kernel, dim3(Bn * Sn / 4), dim3(256), 0, stream, ws, out, grp);
    hipLaunchKernelGGL(mlp_kernel, dim3(Bn * Sn), dim3(256), 0, stream,
                       xyz, feat, ws, grp, b1, b2, b3, out);
}

// Round 11
// 1776.927 us; speedup vs baseline: 1.3079x; 1.3079x over previous
//
#include <hip/hip_runtime.h>

// Problem constants
#define Bn 4
#define Nn 8192
#define Dn 64
#define Sn 2048
#define Kn 32
#define R2c 0.04f          // f32(0.2*0.2)
#define OUT_XYZ (Bn*Sn*3)  // 24576 floats of new_xyz, then feats

// Workspace layout (units = 4-byte elements)
#define WS_P4  0            // [B*N] float4 {x,y,z,0}
#define WS_WB1 131072       // bf16 W1' [64][96]  (feat-first permute, zero pad)
#define WS_WB2 134144       // bf16 W2  [128][64]
#define WS_WB3 138240       // bf16 W3  [256][128]
#define WS_GRP 154624       // int grp_idx [B*S][K]

#define HSTR 136            // bf16 LDS row stride (128 max C + 8 pad)

typedef __attribute__((ext_vector_type(8))) short short8;
typedef __attribute__((ext_vector_type(4))) float floatx4;
typedef __attribute__((ext_vector_type(2))) float float2v;
typedef unsigned long long ull;

// float -> bf16 (RNE) without relying on header APIs
__device__ __forceinline__ unsigned short f2bf(float f) {
    unsigned u = __float_as_uint(f);
    return (unsigned short)((u + 0x7FFFu + ((u >> 16) & 1u)) >> 16);
}

// ---------------------------------------------------------------------------
// Prep: xyz -> float4 array; weights -> bf16 [O][Cp] row-major.
// ---------------------------------------------------------------------------
__global__ __launch_bounds__(256) void prep_kernel(const float* __restrict__ xyz,
                                                   const float* __restrict__ W1,
                                                   const float* __restrict__ W2,
                                                   const float* __restrict__ W3,
                                                   float* __restrict__ ws) {
    int id = blockIdx.x * 256 + threadIdx.x;
    if (id < Bn * Nn) {
        float4* p4 = (float4*)(ws + WS_P4);
        p4[id] = make_float4(xyz[id * 3 + 0], xyz[id * 3 + 1], xyz[id * 3 + 2], 0.f);
    }
    int i1 = id - Bn * Nn;
    if (i1 >= 0 && i1 < 64 * 96) {
        int o = i1 / 96, c = i1 % 96;
        float v = (c < 64) ? W1[o * 67 + 3 + c] : (c < 67 ? W1[o * 67 + (c - 64)] : 0.f);
        ((unsigned short*)(ws + WS_WB1))[i1] = f2bf(v);
    }
    int i2 = i1 - 64 * 96;
    if (i2 >= 0 && i2 < 128 * 64)
        ((unsigned short*)(ws + WS_WB2))[i2] = f2bf(W2[i2]);
    int i3 = i2 - 128 * 64;
    if (i3 >= 0 && i3 < 256 * 128)
        ((unsigned short*)(ws + WS_WB3))[i3] = f2bf(W3[i3]);
}

// Fused wave-64 lexicographic max of 64-bit keys (hi=dist bits, lo=payload).
// One DPP ladder; 0-injection from bound_ctrl can never win. Result
// broadcast via 2 readlanes from lane 63 (SGPR-uniform).
__device__ __forceinline__ ull wave_kmax_dpp(ull k) {
    unsigned lo = (unsigned)k, hi = (unsigned)(k >> 32);
#define KRUNG(ctl)                                                                          \
    {                                                                                       \
        unsigned tlo = (unsigned)__builtin_amdgcn_update_dpp(0, (int)lo, ctl, 0xf, 0xf, true); \
        unsigned thi = (unsigned)__builtin_amdgcn_update_dpp(0, (int)hi, ctl, 0xf, 0xf, true); \
        ull t = ((ull)thi << 32) | tlo;                                                     \
        ull c = ((ull)hi << 32) | lo;                                                       \
        if (t > c) { hi = thi; lo = tlo; }                                                  \
    }
    KRUNG(0x111) KRUNG(0x112) KRUNG(0x114) KRUNG(0x118) KRUNG(0x142) KRUNG(0x143)
#undef KRUNG
    hi = (unsigned)__builtin_amdgcn_readlane((int)hi, 63);
    lo = (unsigned)__builtin_amdgcn_readlane((int)lo, 63);
    return ((ull)hi << 32) | lo;
}

// ---------------------------------------------------------------------------
// Farthest point sampling — FINAL (R8 config, session minimum: fps ~1504us).
//
// Structure: 512 thr (8 waves) x 16 pts/thread. Prologue z-sorts the 8192
// points (256-bin counting sort) into a 128KB LDS table sP4 (x,y,z,origIdx);
// wave w owns sorted slots [w*1024,(w+1)*1024) in REGISTERS. Per step:
// conservative per-slab z-bbox skip (bit-exact: skip implies the min-update
// is the identity for every slab point since dists only decrease), pk-packed
// distance update (2 pts/instruction, bit-exact per element), lane-tie
// recovery tree, ONE fused u64 DPP ladder (max dist, then min origIdx via
// lo=(8191-orig)<<13|slot), parity-double-buffered 8-key LDS exchange with
// ONE barrier/step, 7-compare key tree, broadcast LDS winner fetch.
// Per-step centroid record goes to LDS sHist (global stores inside the loop
// would add a vmcnt(0) drain at the barrier); coalesced dump after the loop.
//
// Falsified alternatives (counter-evidenced, do not revisit):
//  - dist state in LDS (R7: 8-way write bank conflicts, 1.5M SQ_LDS_BANK_CONFLICT)
//  - all state in one wave's registers (R6: scratch spill, FETCH 3x)
//  - points re-read from LDS in the loop (R9: +225 cyc/step lgkm waits)
//  - payload-carrying exchange replacing the winner fetch (R10: +550 cyc/step)
//
// Plateau arithmetic: 2048 strictly-sequential steps x ~1760 cyc/step
// (active-wave update issue ~400-800 cyc at 2 waves/SIMD + DPP ladder dep
// chains + barrier + tree + fetch) on 4 of 256 CUs. VALUBusy 0.66% global /
// HBM 0.003% — latency-bound, not a HW roofline.
// ---------------------------------------------------------------------------
__global__ __launch_bounds__(512, 2) void fps_kernel(const float* __restrict__ ws,
                                                     float* __restrict__ out_xyz) {
    #pragma clang fp contract(off)
    const int b = blockIdx.x;
    const int tid = threadIdx.x;
    const int lane = tid & 63;
    const int wv = tid >> 6;
    const float4* p4 = (const float4*)(ws + WS_P4) + b * Nn;

    __shared__ __align__(16) float4 sP4[Nn];   // 128 KB sorted point table
    __shared__ float sHist[Sn * 3];            // 24 KB per-step centroid record
    __shared__ ull sKey[2][8];
    __shared__ int sH[256];                    // histogram
    __shared__ int sC[256];                    // cursors (exclusive starts)

    // ---- load original points (coalesced) ----
    float4 t4[16];
    #pragma unroll
    for (int j = 0; j < 16; j++) t4[j] = p4[j * 512 + tid];

    // ---- histogram over 256 z-bins ----
    for (int i = tid; i < 256; i += 512) sH[i] = 0;
    __syncthreads();
    int slt[16];
    #pragma unroll
    for (int j = 0; j < 16; j++) {
        int bin = (int)(t4[j].z * 256.0f);
        bin = bin < 0 ? 0 : (bin > 255 ? 255 : bin);
        slt[j] = bin;
        atomicAdd(&sH[bin], 1);
    }
    __syncthreads();

    // ---- exclusive scan of 256 bins (wave 0, 4 bins/lane) ----
    if (tid < 64) {
        int b4 = tid * 4;
        int h0 = sH[b4], h1 = sH[b4 + 1], h2 = sH[b4 + 2], h3 = sH[b4 + 3];
        int sum = h0 + h1 + h2 + h3;
        int inc = sum;
        #pragma unroll
        for (int off = 1; off < 64; off <<= 1) {
            int o = __shfl_up(inc, off);
            if (tid >= off) inc += o;
        }
        int exc = inc - sum;
        sC[b4]     = exc;
        sC[b4 + 1] = exc + h0;
        sC[b4 + 2] = exc + h0 + h1;
        sC[b4 + 3] = exc + h0 + h1 + h2;
    }
    __syncthreads();

    // ---- claim unique sorted slots, scatter into the table ----
    #pragma unroll
    for (int j = 0; j < 16; j++)
        slt[j] = atomicAdd(&sC[slt[j]], 1);
    #pragma unroll
    for (int j = 0; j < 16; j++)
        sP4[slt[j]] = make_float4(t4[j].x, t4[j].y, t4[j].z,
                                  __int_as_float(j * 512 + tid));
    __syncthreads();

    // ---- slab read: wave wv owns slots [wv*1024, wv*1024+1024) ----
    float2v pX[8], pY[8], pZ[8], dI[8];
    unsigned loA[8], loB[8];
    const int sbase = wv * 1024 + lane * 2;
    #pragma unroll
    for (int u = 0; u < 8; u++) {
        int sa = sbase + u * 128;
        float4 va = sP4[sa];
        float4 vb = sP4[sa + 1];
        pX[u].x = va.x; pX[u].y = vb.x;
        pY[u].x = va.y; pY[u].y = vb.y;
        pZ[u].x = va.z; pZ[u].y = vb.z;
        unsigned ogA = (unsigned)__float_as_int(va.w);
        unsigned ogB = (unsigned)__float_as_int(vb.w);
        loA[u] = ((8191u - ogA) << 13) | (unsigned)sa;
        loB[u] = ((8191u - ogB) << 13) | (unsigned)(sa + 1);
        dI[u].x = 1e10f; dI[u].y = 1e10f;
    }
    #pragma unroll
    for (int u = 0; u < 8; u++)
        asm volatile("" : "+v"(pX[u]), "+v"(pY[u]), "+v"(pZ[u]));

    // ---- wave z-bbox (exact min/max butterfly, one time) ----
    float zl = fminf(pZ[0].x, pZ[0].y);
    float zh = fmaxf(pZ[0].x, pZ[0].y);
    #pragma unroll
    for (int u = 1; u < 8; u++) {
        zl = fminf(zl, fminf(pZ[u].x, pZ[u].y));
        zh = fmaxf(zh, fmaxf(pZ[u].x, pZ[u].y));
    }
    #pragma unroll
    for (int off = 1; off < 64; off <<= 1) {
        zl = fminf(zl, __shfl_xor(zl, off));
        zh = fmaxf(zh, __shfl_xor(zh, off));
    }

    // ---- main FPS loop ----
    float4 c0 = p4[0];
    float cx = c0.x, cy = c0.y, cz = c0.z;
    float wmaxC = 1e30f;     // cached wave max dist (forces first step active)
    ull bestK = 0;           // cached wave best key

    for (int s = 0; s < Sn; s++) {
        const int par = s & 1;
        if (tid == 0) {       // LDS record: no vmcnt at the barrier
            sHist[s * 3 + 0] = cx;
            sHist[s * 3 + 1] = cy;
            sHist[s * 3 + 2] = cz;
        }

        // conservative slab distance: skip only if provably no dist changes
        float dzb = fmaxf(fmaxf(zl - cz, cz - zh), 0.0f);
        float dz2s = dzb * dzb * 0.999999f;
        if (dz2s < wmaxC) {   // wave-uniform branch
            float nxs = -cx, nys = -cy, nzs = -cz;
            float2v nX, nY, nZ;
            nX.x = nxs; nX.y = nxs;
            nY.x = nys; nY.y = nys;
            nZ.x = nzs; nZ.y = nzs;

            float lv = -1.0f;
            #pragma unroll
            for (int u = 0; u < 8; u++) {
                float2v dx, dy, dz_, xx, yy, zz, s1, d2;
                asm("v_pk_add_f32 %0, %1, %2" : "=v"(dx) : "v"(pX[u]), "v"(nX));
                asm("v_pk_add_f32 %0, %1, %2" : "=v"(dy) : "v"(pY[u]), "v"(nY));
                asm("v_pk_add_f32 %0, %1, %2" : "=v"(dz_) : "v"(pZ[u]), "v"(nZ));
                asm("v_pk_mul_f32 %0, %1, %1" : "=v"(xx) : "v"(dx));
                asm("v_pk_mul_f32 %0, %1, %1" : "=v"(yy) : "v"(dy));
                asm("v_pk_mul_f32 %0, %1, %1" : "=v"(zz) : "v"(dz_));
                asm("v_pk_add_f32 %0, %1, %2" : "=v"(s1) : "v"(xx), "v"(yy));
                asm("v_pk_add_f32 %0, %1, %2" : "=v"(d2) : "v"(s1), "v"(zz));
                float mx = fminf(dI[u].x, d2.x);
                float my = fminf(dI[u].y, d2.y);
                dI[u].x = mx; dI[u].y = my;
                lv = fmaxf(fmaxf(lv, mx), my);   // v_max3_f32
            }

            // lane-tie recovery: max lo among THIS lane's points at lv
            unsigned c[16];
            #pragma unroll
            for (int u = 0; u < 8; u++) {
                c[2 * u]     = (dI[u].x == lv) ? loA[u] : 0u;
                c[2 * u + 1] = (dI[u].y == lv) ? loB[u] : 0u;
            }
            #pragma unroll
            for (int st = 1; st < 16; st <<= 1)
                #pragma unroll
                for (int i = 0; i < 16; i += 2 * st)
                    c[i] = (c[i + st] > c[i]) ? c[i + st] : c[i];

            // fused lexicographic wave reduce
            ull k = ((ull)__float_as_uint(lv) << 32) | (ull)c[0];
            bestK = wave_kmax_dpp(k);
            wmaxC = __uint_as_float((unsigned)(bestK >> 32));
        }

        if (lane == 0) sKey[par][wv] = bestK;
        __syncthreads();

        ull a0 = sKey[par][0], a1 = sKey[par][1];
        ull a2 = sKey[par][2], a3 = sKey[par][3];
        ull a4 = sKey[par][4], a5 = sKey[par][5];
        ull a6 = sKey[par][6], a7 = sKey[par][7];
        a0 = (a1 > a0) ? a1 : a0;
        a2 = (a3 > a2) ? a3 : a2;
        a4 = (a5 > a4) ? a5 : a4;
        a6 = (a7 > a6) ? a7 : a6;
        a0 = (a2 > a0) ? a2 : a0;
        a4 = (a6 > a4) ? a6 : a4;
        ull kk = (a4 > a0) ? a4 : a0;

        // winner coords: broadcast LDS read via slot payload
        int slot = (int)(kk & 0x1FFFull);
        float4 c4 = sP4[slot];
        cx = c4.x; cy = c4.y; cz = c4.z;
    }

    __syncthreads();
    float4* o4 = (float4*)(out_xyz + b * Sn * 3);
    const float4* h4 = (const float4*)sHist;
    #pragma unroll
    for (int i = tid; i < Sn * 3 / 4; i += 512) o4[i] = h4[i];
}

// ---------------------------------------------------------------------------
// Ball query (unchanged; exact-decision verified: absmax 0.0).
// ---------------------------------------------------------------------------
__global__ __launch_bounds__(256) void ballq_kernel(const float* __restrict__ ws,
                                                    const float* __restrict__ newxyz,
                                                    int* __restrict__ grp) {
    #pragma clang fp contract(off)
    int t = blockIdx.x * 256 + threadIdx.x;
    int wid = t >> 6;
    int lane = t & 63;
    int b = wid >> 11;
    const float4* p4 = (const float4*)(ws + WS_P4) + b * Nn;

    float nx = newxyz[wid * 3 + 0], ny = newxyz[wid * 3 + 1], nz = newxyz[wid * 3 + 2];
    float a2 = (nx * nx + ny * ny) + nz * nz;

    int total = 0;
    int firstp = 0;
    for (int c = 0; c < Nn / 64; c++) {
        int p = c * 64 + lane;
        float4 v = p4[p];
        float x = v.x, y = v.y, z = v.z;
        float bv = (x * x + y * y) + z * z;
        float dot = __builtin_fmaf(nx, x, 0.0f);
        dot = __builtin_fmaf(ny, y, dot);
        dot = __builtin_fmaf(nz, z, dot);
        float sq = (a2 + bv) - 2.0f * dot;
        bool hit = !(sq > R2c);
        unsigned long long mask = __ballot(hit);
        if (mask) {
            if (total == 0) firstp = c * 64 + (__ffsll(mask) - 1);
            int rank = __popcll(mask & ((1ull << lane) - 1ull));
            int slot = total + rank;
            if (hit && slot < Kn) grp[wid * Kn + slot] = p;
            total += (int)__popcll(mask);
            if (total >= Kn) break;
        }
    }
    if (lane >= total && lane < Kn) grp[wid * Kn + lane] = firstp;
}

// ---------------------------------------------------------------------------
// MFMA MLP (unchanged): one group per block, 256 threads = 4 waves.
// ---------------------------------------------------------------------------
template<int KB, int O>
__device__ __forceinline__ void mfma_layer(const unsigned short* __restrict__ X,
                                           unsigned short* __restrict__ Y,
                                           const unsigned short* __restrict__ wb,
                                           const float* __restrict__ bias,
                                           int lane, int wv) {
    const int Cp = KB * 32;
    const int mt = wv & 1;
    const int mrow = mt * 16 + (lane & 15);
    const int quad = lane >> 4;

    short8 a[KB];
    #pragma unroll
    for (int kb = 0; kb < KB; kb++)
        a[kb] = *(const short8*)&X[mrow * HSTR + kb * 32 + quad * 8];

    for (int nt = (wv >> 1); nt < O / 16; nt += 2) {
        int n0 = nt * 16;
        float bv = bias[n0 + (lane & 15)];
        floatx4 acc = {bv, bv, bv, bv};
        #pragma unroll
        for (int kb = 0; kb < KB; kb++) {
            short8 bf = *(const short8*)&wb[(n0 + (lane & 15)) * Cp + kb * 32 + quad * 8];
            acc = __builtin_amdgcn_mfma_f32_16x16x32_bf16(a[kb], bf, acc, 0, 0, 0);
        }
        #pragma unroll
        for (int r = 0; r < 4; r++) {
            float v = fmaxf(acc[r], 0.f);
            int m = mt * 16 + quad * 4 + r;
            Y[m * HSTR + n0 + (lane & 15)] = f2bf(v);
        }
    }
}

__global__ __launch_bounds__(256) void mlp_kernel(const float* __restrict__ xyz,
                                                  const float* __restrict__ feat,
                                                  const float* __restrict__ ws,
                                                  const int* __restrict__ grp,
                                                  const float* __restrict__ b1,
                                                  const float* __restrict__ b2,
                                                  const float* __restrict__ b3,
                                                  float* __restrict__ out) {
    __shared__ __align__(16) unsigned short hA[32 * HSTR];
    __shared__ __align__(16) unsigned short hB[32 * HSTR];
    __shared__ float mxs[2][256];
    __shared__ int   sIdx[Kn];
    __shared__ float sCent[3];

    int g = blockIdx.x;            // b*S + s
    int b = g >> 11;
    int tid = threadIdx.x;
    int lane = tid & 63, wv = tid >> 6;

    if (tid < Kn) sIdx[tid] = grp[g * Kn + tid];
    if (tid == 0) { sCent[0] = out[g*3]; sCent[1] = out[g*3+1]; sCent[2] = out[g*3+2]; }
    // zero hA (pad cols must be 0 for the K=96 layer)
    {
        short8 z = {0,0,0,0,0,0,0,0};
        for (int i = tid; i < 32 * HSTR / 8; i += 256)
            ((short8*)hA)[i] = z;
    }
    __syncthreads();

    { // stage h0: feats -> cols 0..63 (bf16x8 vector writes), xyz -> 64..66
        int m = tid >> 3, m8 = tid & 7;
        int idx = sIdx[m];
        int base = b * Nn + idx;
        const float4* f4 = (const float4*)(feat + base * 64 + m8 * 8);
        float4 va = f4[0], vb = f4[1];
        short8 pk;
        pk[0] = (short)f2bf(va.x); pk[1] = (short)f2bf(va.y);
        pk[2] = (short)f2bf(va.z); pk[3] = (short)f2bf(va.w);
        pk[4] = (short)f2bf(vb.x); pk[5] = (short)f2bf(vb.y);
        pk[6] = (short)f2bf(vb.z); pk[7] = (short)f2bf(vb.w);
        *(short8*)&hA[m * HSTR + m8 * 8] = pk;
        if (m8 == 0) {
            hA[m * HSTR + 64] = f2bf(xyz[base * 3 + 0] - sCent[0]);
            hA[m * HSTR + 65] = f2bf(xyz[base * 3 + 1] - sCent[1]);
            hA[m * HSTR + 66] = f2bf(xyz[base * 3 + 2] - sCent[2]);
        }
    }
    __syncthreads();

    const unsigned short* wb1 = (const unsigned short*)(ws + WS_WB1);
    const unsigned short* wb2 = (const unsigned short*)(ws + WS_WB2);
    const unsigned short* wb3 = (const unsigned short*)(ws + WS_WB3);

    mfma_layer<3, 64>(hA, hB, wb1, b1, lane, wv);     // 96 -> 64
    __syncthreads();
    mfma_layer<2, 128>(hB, hA, wb2, b2, lane, wv);    // 64 -> 128
    __syncthreads();

    { // L3 (128 -> 256) + fused maxpool
        const int mt = wv & 1;
        const int mrow = mt * 16 + (lane & 15);
        const int quad = lane >> 4;
        short8 a[4];
        #pragma unroll
        for (int kb = 0; kb < 4; kb++)
            a[kb] = *(const short8*)&hA[mrow * HSTR + kb * 32 + quad * 8];
        for (int nt = (wv >> 1); nt < 16; nt += 2) {
            int n0 = nt * 16;
            float bv = b3[n0 + (lane & 15)];
            floatx4 acc = {bv, bv, bv, bv};
            #pragma unroll
            for (int kb = 0; kb < 4; kb++) {
                short8 bf = *(const short8*)&wb3[(n0 + (lane & 15)) * 128 + kb * 32 + quad * 8];
                acc = __builtin_amdgcn_mfma_f32_16x16x32_bf16(a[kb], bf, acc, 0, 0, 0);
            }
            float pm = fmaxf(fmaxf(fmaxf(acc[0], acc[1]), fmaxf(acc[2], acc[3])), 0.f);
            pm = fmaxf(pm, __shfl_xor(pm, 16));   // reduce across the 4 quads
            pm = fmaxf(pm, __shfl_xor(pm, 32));
            if (lane < 16) mxs[mt][n0 + lane] = pm;
        }
    }
    __syncthreads();

    out[OUT_XYZ + g * 256 + tid] = fmaxf(mxs[0][tid], mxs[1][tid]);
}

// ---------------------------------------------------------------------------
extern "C" void kernel_launch(void* const* d_in, const int* in_sizes, int n_in,
                              void* d_out, int out_size, void* d_ws, size_t ws_size,
                              hipStream_t stream) {
    const float* xyz  = (const float*)d_in[0];
    const float* feat = (const float*)d_in[1];
    const float* W1   = (const float*)d_in[2];
    const float* b1   = (const float*)d_in[3];
    const float* W2   = (const float*)d_in[4];
    const float* b2   = (const float*)d_in[5];
    const float* W3   = (const float*)d_in[6];
    const float* b3   = (const float*)d_in[7];
    float* out = (float*)d_out;
    float* ws  = (float*)d_ws;
    int*   grp = (int*)d_ws + WS_GRP;

    hipLaunchKernelGGL(prep_kernel, dim3(312), dim3(256), 0, stream, xyz, W1, W2, W3, ws);
    hipLaunchKernelGGL(fps_kernel, dim3(Bn), dim3(512), 0, stream, ws, out);
    hipLaunchKernelGGL(ballq_kernel, dim3(Bn * Sn / 4), dim3(256), 0, stream, ws, out, grp);
    hipLaunchKernelGGL(mlp_kernel, dim3(Bn * Sn), dim3(256), 0, stream,
                       xyz, feat, ws, grp, b1, b2, b3, out);
}